// Round 1
// baseline (220.337 us; speedup 1.0000x reference)
//
#include <hip/hip_runtime.h>
#include <hip/hip_bf16.h>

// GCN layer: out = relu( A0 @ (X W0) + A1 @ (X W1) + bias )
// N=50000, D=128, E=800000 per adjacency, fp32 in/out, COO edges.
//
// R14 (this round):
//   prep        W0/W1 -> bf16 transposed (8 blocks, k-split) + zero cur. (verbatim)
//   mid_kernel  FUSED dispatch: blocks [0,392) = fill role, [392,3517) = gemm role.
//     fill6: 512 thr / 4096 edges. Wave-shuffle scan (5 barriers vs fill5's 20),
//            int4/float4 edge loads, bstart/part arrays dropped (start[k] ==
//            lcur[k-1] after scatter). ~70 KB LDS -> 2 blocks/CU, 392 blocks
//            cover all 256 CUs (fill5: 196 blocks, 1/CU, 120 KB).
//     gemm:  verbatim R13 16-row MFMA tile; shares the LDS union (occupancy
//            2 blocks/CU = 16 waves; MFMA load is trivial, streaming is f4).
//     Roles are data-independent; fill blocks dispatch first so gemm streams
//     in behind the barrier-heavy fill blocks (overlap, one less launch).
//   aggregate9  verbatim R11/R12 (measured 61-62.7us, FETCH pinned ~177MB =
//               the random-gather ceiling across 4 structural variants).
// NEVER use fp32 LDS atomics in the per-record loop (R4: 1234us, R9: 1216us).

#define BROWS 32                   // bucket = 32 dst rows
#define NBUCK 1563                 // ceil(50000/32)
#define NB2 2048                   // padded bin count
#define BCAP 704                   // records per (bucket,adj); mean 512, +8.5 sigma
#define ACAP (2 * BCAP)
#define FT6 4096                   // fill tile (edges per block) = 512 thr * 8
#define PREROWS 65536              // adj stride in unified pre

typedef __attribute__((ext_vector_type(8))) short bf16x8;
typedef __attribute__((ext_vector_type(4))) float f32x4;

__device__ inline unsigned short f2bf(float f) {
    union { float f; unsigned u; } v; v.f = f;
    unsigned r = v.u + 0x7fff + ((v.u >> 16) & 1);   // round-nearest-even
    return (unsigned short)(r >> 16);
}

// blocks 0..7: W transpose (4 k-slices x 2 Ws). block 8: zero cur.
__global__ __launch_bounds__(256) void prep_kernel(
    const float* __restrict__ W0, const float* __restrict__ W1,
    unsigned short* __restrict__ wt0, unsigned short* __restrict__ wt1,
    int* __restrict__ cur, int ncur)
{
    const int bid = blockIdx.x;
    const int tid = threadIdx.x;
    if (bid >= 8) {
        for (int i = tid; i < ncur; i += 256) cur[i] = 0;
        return;
    }
    const int which = bid >> 2;
    const int k0 = (bid & 3) * 32;
    const float* __restrict__ W = which ? W1 : W0;
    unsigned short* __restrict__ wt = which ? wt1 : wt0;
    for (int i = tid; i < 32 * 128; i += 256) {
        int k = k0 + (i >> 7), n = i & 127;
        wt[n * 128 + k] = f2bf(W[k * 128 + n]);
    }
}

// ---- fused mid kernel: fill role + gemm role share one LDS union ----
struct FillSM {
    int2 srt[FT6];                       // 32 KB sorted records
    alignas(16) int lcnt[NB2];           // 8 KB per-bucket counts
    alignas(16) int lcur[NB2];           // 8 KB scatter cursors (end == next start)
    unsigned short skey[FT6];            // 8 KB bucket of each sorted record
    int gpos[NBUCK];                     // 6.25 KB global base per bucket
    int glim[NBUCK];                     // 6.25 KB
    int wsum[8];                         // wave scan partials
    int total;
};
struct GemmSM {
    unsigned short sA[16][136];          // bf16 A-tile, pad: 272B row
    short ctile[8][16][40];              // per-wave 16x32 C tile (+pad)
};
union MidSM { FillSM f; GemmSM g; };     // ~69.9 KB -> 2 blocks/CU

__global__ __launch_bounds__(512) void mid_kernel(
    const float* __restrict__ x,
    const unsigned short* __restrict__ wt0,
    const unsigned short* __restrict__ wt1,
    unsigned short* __restrict__ pre,    // unified: adj*PREROWS + row
    const int* __restrict__ ei0, const int* __restrict__ ei1,
    const float* __restrict__ ev0, const float* __restrict__ ev1,
    int* __restrict__ cur, int2* __restrict__ recs,
    int E, int N, int nfill)
{
    __shared__ MidSM sm;
    const int tid = threadIdx.x;
    const int bx = blockIdx.x;

    if (bx < nfill) {
        // ================= fill role =================
        FillSM& F = sm.f;
        const int a = bx & 1;
        const int e0 = (bx >> 1) * FT6;
        const int* __restrict__ ei = a ? ei1 : ei0;
        const float* __restrict__ ev = a ? ev1 : ev0;

        ((int4*)F.lcnt)[tid] = make_int4(0, 0, 0, 0);
        __syncthreads();

        // load 8 consecutive edges per thread (int4/float4 vector loads)
        const int eb = e0 + tid * 8;
        int dd[8], ss[8]; float vv[8];
        if (e0 + FT6 <= E) {
            int4 d0 = *(const int4*)(ei + eb);
            int4 d1 = *(const int4*)(ei + eb + 4);
            int4 s0 = *(const int4*)(ei + E + eb);
            int4 s1 = *(const int4*)(ei + E + eb + 4);
            float4 v0 = *(const float4*)(ev + eb);
            float4 v1 = *(const float4*)(ev + eb + 4);
            dd[0] = d0.x; dd[1] = d0.y; dd[2] = d0.z; dd[3] = d0.w;
            dd[4] = d1.x; dd[5] = d1.y; dd[6] = d1.z; dd[7] = d1.w;
            ss[0] = s0.x; ss[1] = s0.y; ss[2] = s0.z; ss[3] = s0.w;
            ss[4] = s1.x; ss[5] = s1.y; ss[6] = s1.z; ss[7] = s1.w;
            vv[0] = v0.x; vv[1] = v0.y; vv[2] = v0.z; vv[3] = v0.w;
            vv[4] = v1.x; vv[5] = v1.y; vv[6] = v1.z; vv[7] = v1.w;
        } else {
#pragma unroll
            for (int j = 0; j < 8; ++j) {
                int e = eb + j;
                if (e < E) { dd[j] = ei[e]; ss[j] = ei[E + e]; vv[j] = ev[e]; }
            }
        }
        int key8[8]; int2 rec[8];
#pragma unroll
        for (int j = 0; j < 8; ++j) {
            if (eb + j < E) {
                key8[j] = dd[j] >> 5;
                rec[j] = make_int2(((dd[j] & 31) << 17) | (a << 16) | ss[j],
                                   __float_as_int(vv[j]));
                atomicAdd(&F.lcnt[key8[j]], 1);
            } else key8[j] = -1;
        }
        __syncthreads();

        // wave-shuffle exclusive scan over 2048 bins (4 per thread)
        const int lane = tid & 63;
        const int wv = tid >> 6;
        int4 c4 = ((const int4*)F.lcnt)[tid];
        int cc[4] = { c4.x, c4.y, c4.z, c4.w };
        int tsum = cc[0] + cc[1] + cc[2] + cc[3];
        int p = tsum;
#pragma unroll
        for (int o = 1; o < 64; o <<= 1) {
            int t = __shfl_up(p, o);
            if (lane >= o) p += t;
        }
        if (lane == 63) F.wsum[wv] = p;
        __syncthreads();
        int wbase = 0;
#pragma unroll
        for (int w2 = 0; w2 < 7; ++w2) wbase += (w2 < wv) ? F.wsum[w2] : 0;
        if (tid == 511) F.total = wbase + p;
        int off = wbase + p - tsum;          // exclusive start of bin 4*tid
        const int k0 = 4 * tid;
#pragma unroll
        for (int h = 0; h < 4; ++h) {
            F.lcur[k0 + h] = off;
            if (k0 + h < NBUCK && cc[h] > 0) {
                int bin = (k0 + h) * 2 + a;
                int g = atomicAdd(&cur[bin], cc[h]);
                int lim = BCAP - g; if (lim < 0) lim = 0;   // overflow guard
                F.gpos[k0 + h] = bin * BCAP + g;
                F.glim[k0 + h] = lim;
            }
            off += cc[h];
        }
        __syncthreads();

        // scatter into LDS sorted by bucket
#pragma unroll
        for (int j = 0; j < 8; ++j) {
            if (key8[j] >= 0) {
                int pp = atomicAdd(&F.lcur[key8[j]], 1);
                F.srt[pp] = rec[j];
                F.skey[pp] = (unsigned short)key8[j];
            }
        }
        __syncthreads();

        // coalesced write-out; start[k] == lcur[k-1] (ends are next starts)
        const int total = F.total;
        for (int i = tid; i < total; i += 512) {
            int k = F.skey[i];
            int st = k ? F.lcur[k - 1] : 0;
            int r = i - st;
            if (r < F.glim[k]) recs[F.gpos[k] + r] = F.srt[i];
        }
    } else {
        // ================= gemm role (verbatim R13 structure) =================
        GemmSM& G = sm.g;
        const int m0 = (bx - nfill) * 16;

        // stage A: 512 float4 loads (1 per thread), convert, store 8B to LDS
        {
            int r = tid >> 5;                 // 32 float4 per row
            int c4i = (tid & 31) << 2;
            float4 v = *(const float4*)&x[(m0 + r) * 128 + c4i];
            ushort4 s;
            s.x = f2bf(v.x); s.y = f2bf(v.y); s.z = f2bf(v.z); s.w = f2bf(v.w);
            *(ushort4*)&G.sA[r][c4i] = s;
        }
        __syncthreads();

        const int w = tid >> 6;
        const int lane = tid & 63;
        const int adj = w >> 2;
        const int wq = w & 3;
        const unsigned short* __restrict__ wt = adj ? wt1 : wt0;
        unsigned short* __restrict__ po = pre + (size_t)adj * PREROWS * 128;
        const int l15 = lane & 15;
        const int quad = lane >> 4;
        const int nA = wq * 32 + l15;

        f32x4 c0 = {0.f, 0.f, 0.f, 0.f};
        f32x4 c1 = {0.f, 0.f, 0.f, 0.f};
#pragma unroll
        for (int k0 = 0; k0 < 128; k0 += 32) {
            union { bf16x8 v; ushort4 h[2]; } au;
            au.h[0] = *(const ushort4*)&G.sA[l15][k0 + quad * 8];
            au.h[1] = *(const ushort4*)&G.sA[l15][k0 + quad * 8 + 4];
            bf16x8 b0 = *(const bf16x8*)&wt[nA * 128 + k0 + quad * 8];
            bf16x8 b1 = *(const bf16x8*)&wt[(nA + 16) * 128 + k0 + quad * 8];
            c0 = __builtin_amdgcn_mfma_f32_16x16x32_bf16(au.v, b0, c0, 0, 0, 0);
            c1 = __builtin_amdgcn_mfma_f32_16x16x32_bf16(au.v, b1, c1, 0, 0, 0);
        }

        // stage C into wave-private LDS tile (wave-internal dep: no barrier)
#pragma unroll
        for (int i = 0; i < 4; ++i) {
            G.ctile[w][quad * 4 + i][l15]      = (short)f2bf(c0[i]);
            G.ctile[w][quad * 4 + i][16 + l15] = (short)f2bf(c1[i]);
        }
        const int rr = lane >> 2, cg = (lane & 3) * 8;
        ushort4 s0 = *(ushort4*)&G.ctile[w][rr][cg];
        ushort4 s1 = *(ushort4*)&G.ctile[w][rr][cg + 4];
        int row = m0 + rr;                        // N % 16 == 0, always < N
        *(ushort4*)&po[row * 128 + wq * 32 + cg] = s0;
        *(ushort4*)&po[row * 128 + wq * 32 + cg + 4] = s1;
    }
}

// One block per 32-row bucket (256 thr = 4 waves, wave wv -> rows wv*8..+7).
// Stage records in LDS, counting-sort FULL records by row (32 keys), then
// 8x-unrolled independent gathers from the unified pre, register accumulate,
// fused bias+relu writeout. (Verbatim R11/R12 structure: measured 61-62.7us.)
__global__ __launch_bounds__(256, 6) void aggregate9_kernel(
    const int* __restrict__ cur, const int2* __restrict__ recs,
    const unsigned short* __restrict__ pre,
    const float* __restrict__ bias,
    float* __restrict__ out, int N)
{
    __shared__ int2 srec[ACAP];             // 11.3 KB staged raw
    __shared__ int2 srt[ACAP];              // 11.3 KB row-sorted
    __shared__ int lcnt[32];
    __shared__ int lstart[32];
    __shared__ int lcur[32];

    const int b = blockIdx.x;
    const int tid = threadIdx.x;

    int n0 = cur[2 * b];     if (n0 > BCAP) n0 = BCAP;
    int n1 = cur[2 * b + 1]; if (n1 > BCAP) n1 = BCAP;
    const int total = n0 + n1;
    const int base0 = (2 * b) * BCAP, base1 = (2 * b + 1) * BCAP;

    if (tid < 32) lcnt[tid] = 0;
    __syncthreads();

    // stage + per-row counts (int LDS atomics)
    for (int i = tid; i < total; i += 256) {
        int2 r = (i < n0) ? recs[base0 + i] : recs[base1 + i - n0];
        srec[i] = r;
        atomicAdd(&lcnt[(r.x >> 17) & 31], 1);
    }
    __syncthreads();

    // wave 0 lanes 0-31: shfl exclusive scan of 32 counters
    if (tid < 32) {
        int cme = lcnt[tid];
        int p = cme;
#pragma unroll
        for (int o = 1; o < 32; o <<= 1) {
            int t = __shfl_up(p, o);
            if (tid >= o) p += t;
        }
        lstart[tid] = p - cme;
        lcur[tid] = p - cme;
    }
    __syncthreads();

    // scatter full records sorted by row
    for (int i = tid; i < total; i += 256) {
        int2 r = srec[i];
        srt[atomicAdd(&lcur[(r.x >> 17) & 31], 1)] = r;
    }
    __syncthreads();

    // gather: wave wv owns rows wv*8 .. wv*8+7; both adjacencies in one run
    const int wv = tid >> 6;
    const int lane = tid & 63;
    const float2 bi = *(const float2*)&bias[lane * 2];

#define GA(r) (*(const unsigned*)&pre[((r).x & 0x1ffff) * 128 + 2 * lane])
#define ACC(r, u) { float v = __int_as_float((r).y);                    \
        acc.x = fmaf(v, __uint_as_float((u) << 16), acc.x);             \
        acc.y = fmaf(v, __uint_as_float((u) & 0xffff0000u), acc.y); }

    for (int t = 0; t < 8; ++t) {
        const int rl = wv * 8 + t;
        const int s = lstart[rl];
        const int e = s + lcnt[rl];
        float2 acc = make_float2(0.f, 0.f);
        int j = s;
        for (; j + 8 <= e; j += 8) {
            int2 r0 = srt[j], r1 = srt[j + 1], r2 = srt[j + 2], r3 = srt[j + 3];
            int2 r4 = srt[j + 4], r5 = srt[j + 5], r6 = srt[j + 6], r7 = srt[j + 7];
            unsigned u0 = GA(r0), u1 = GA(r1), u2 = GA(r2), u3 = GA(r3);
            unsigned u4 = GA(r4), u5 = GA(r5), u6 = GA(r6), u7 = GA(r7);
            ACC(r0, u0); ACC(r1, u1); ACC(r2, u2); ACC(r3, u3);
            ACC(r4, u4); ACC(r5, u5); ACC(r6, u6); ACC(r7, u7);
        }
        for (; j + 4 <= e; j += 4) {
            int2 r0 = srt[j], r1 = srt[j + 1], r2 = srt[j + 2], r3 = srt[j + 3];
            unsigned u0 = GA(r0), u1 = GA(r1), u2 = GA(r2), u3 = GA(r3);
            ACC(r0, u0); ACC(r1, u1); ACC(r2, u2); ACC(r3, u3);
        }
        for (; j < e; ++j) {
            int2 r0 = srt[j];
            unsigned u0 = GA(r0);
            ACC(r0, u0);
        }
        int row = b * BROWS + rl;
        if (row < N) {
            float2 o;
            o.x = fmaxf(acc.x + bi.x, 0.f);
            o.y = fmaxf(acc.y + bi.y, 0.f);
            *(float2*)&out[row * 128 + 2 * lane] = o;
        }
    }
#undef GA
#undef ACC
}

extern "C" void kernel_launch(void* const* d_in, const int* in_sizes, int n_in,
                              void* d_out, int out_size, void* d_ws, size_t ws_size,
                              hipStream_t stream) {
    const float* x    = (const float*)d_in[0];
    const float* W0   = (const float*)d_in[1];
    const float* W1   = (const float*)d_in[2];
    const float* bias = (const float*)d_in[3];
    const float* ev0  = (const float*)d_in[4];
    const float* ev1  = (const float*)d_in[5];
    const int*   ei0  = (const int*)d_in[6];
    const int*   ei1  = (const int*)d_in[7];
    float* out = (float*)d_out;

    const int N = in_sizes[0] / 128;      // 50000
    const int E = in_sizes[4];            // 800000
    const int NBINS2 = NBUCK * 2;         // 3126

    // Workspace layout
    char* w = (char*)d_ws;
    unsigned short* pre = (unsigned short*)w;   w += (size_t)2 * PREROWS * 128 * 2;  // 33.5 MB
    unsigned short* wt0 = (unsigned short*)w;   w += (size_t)128 * 128 * 2;
    unsigned short* wt1 = (unsigned short*)w;   w += (size_t)128 * 128 * 2;
    int* cur = (int*)w;                         w += (size_t)NBINS2 * 4;
    int2* recs = (int2*)w;                      w += (size_t)NBINS2 * BCAP * 8;      // 17.6 MB

    // Phase 0: W -> bf16 transposed + zero cur (one 9-block dispatch)
    prep_kernel<<<9, 256, 0, stream>>>(W0, W1, wt0, wt1, cur, NBINS2);

    // Phase 1+2 fused: fill blocks first (barrier/LDS-bound), gemm streams in
    const int nfill = 2 * ((E + FT6 - 1) / FT6);      // 392
    const int ngemm = N / 16;                          // 3125
    mid_kernel<<<nfill + ngemm, 512, 0, stream>>>(
        x, wt0, wt1, pre, ei0, ei1, ev0, ev1, cur, recs, E, N, nfill);

    // Phase 3: bucket-sorted gather aggregation + bias + relu
    aggregate9_kernel<<<NBUCK, 256, 0, stream>>>(cur, recs, pre, bias, out, N);
}